// Round 1
// baseline (728.634 us; speedup 1.0000x reference)
//
#include <hip/hip_runtime.h>

// Zero the vert_density region (harness poisons d_out with 0xAA each launch).
__global__ __launch_bounds__(256) void zero_vd_kernel(float4* __restrict__ vd4, int n4) {
    int i = blockIdx.x * blockDim.x + threadIdx.x;
    if (i < n4) vd4[i] = make_float4(0.f, 0.f, 0.f, 0.f);
}

__global__ __launch_bounds__(256) void tet_kernel(
    const float* __restrict__ verts,
    const int4*  __restrict__ indices,
    const float* __restrict__ density,
    float* __restrict__ out_area,
    float* __restrict__ out_alpha,
    unsigned int* __restrict__ vd,
    int T)
{
    int i = blockIdx.x * blockDim.x + threadIdx.x;
    if (i >= T) return;

    int4 idx = indices[i];
    float d = density[i];

    const float* p;
    p = verts + idx.x * 3; float v0x = p[0], v0y = p[1], v0z = p[2];
    p = verts + idx.y * 3; float v1x = p[0], v1y = p[1], v1z = p[2];
    p = verts + idx.z * 3; float v2x = p[0], v2y = p[1], v2z = p[2];
    p = verts + idx.w * 3; float v3x = p[0], v3y = p[1], v3z = p[2];

    float e1x = v1x - v0x, e1y = v1y - v0y, e1z = v1z - v0z;
    float e2x = v2x - v0x, e2y = v2y - v0y, e2z = v2z - v0z;
    float e3x = v3x - v0x, e3y = v3y - v0y, e3z = v3z - v0z;

    float det = e1x * (e2y * e3z - e2z * e3y)
              - e1y * (e2x * e3z - e2z * e3x)
              + e1z * (e2x * e3y - e2y * e3x);
    out_area[i] = fabsf(det) * (1.0f / 6.0f);

    float q01 = e1x * e1x + e1y * e1y + e1z * e1z;
    float q02 = e2x * e2x + e2y * e2y + e2z * e2z;
    float q03 = e3x * e3x + e3y * e3y + e3z * e3z;
    float ax, ay, az;
    ax = v1x - v2x; ay = v1y - v2y; az = v1z - v2z;
    float q12 = ax * ax + ay * ay + az * az;
    ax = v1x - v3x; ay = v1y - v3y; az = v1z - v3z;
    float q13 = ax * ax + ay * ay + az * az;
    ax = v2x - v3x; ay = v2y - v3y; az = v2z - v3z;
    float q23 = ax * ax + ay * ay + az * az;

    float mn = fminf(fminf(fminf(q01, q02), fminf(q03, q12)), fminf(q13, q23));
    float el = sqrtf(mn);
    out_alpha[i] = 1.0f - expf(-d * el);

    // Positive floats compare identically as unsigned ints -> atomic uint max == float max.
    unsigned int db = __float_as_uint(d);
    atomicMax(vd + idx.x, db);
    atomicMax(vd + idx.y, db);
    atomicMax(vd + idx.z, db);
    atomicMax(vd + idx.w, db);
}

extern "C" void kernel_launch(void* const* d_in, const int* in_sizes, int n_in,
                              void* d_out, int out_size, void* d_ws, size_t ws_size,
                              hipStream_t stream) {
    const float* verts   = (const float*)d_in[0];
    const int4*  indices = (const int4*)d_in[1];
    const float* density = (const float*)d_in[2];
    int T = in_sizes[2];        // 4,000,000 tets
    int V = in_sizes[0] / 3;    // 1,000,000 vertices

    float* out       = (float*)d_out;
    float* out_area  = out;
    float* out_alpha = out + (size_t)T;
    unsigned int* vd = (unsigned int*)(out + 2 * (size_t)T);

    // Zero vert_density region first (same stream -> ordered before atomics).
    int n4 = V / 4;  // V = 1M, divisible by 4
    int zblock = 256;
    int zgrid = (n4 + zblock - 1) / zblock;
    zero_vd_kernel<<<zgrid, zblock, 0, stream>>>((float4*)vd, n4);

    int block = 256;
    int grid = (T + block - 1) / block;
    tet_kernel<<<grid, block, 0, stream>>>(verts, indices, density,
                                           out_area, out_alpha, vd, T);
}